// Round 5
// baseline (1286.218 us; speedup 1.0000x reference)
//
#include <hip/hip_runtime.h>
#include <hip/hip_bf16.h>

// ---------------------------------------------------------------------------
// GAT encoder, round 5: emulated-fp32 GEMM via hi/lo split bf16 MFMA
// (3 products: Ahi*Bhi + Ahi*Blo + Alo*Bhi, fp32 accum -> ~2^-17 relative).
// Round-5 changes:
//  * GEMM wave tile 128x64 (BM=256,BN=128, 4 waves) for the N=2048 GEMMs:
//    LDS-read demand -25%, MFMA/barrier x2 (LDS-BW was the binding limit).
//    N=512 GEMMs keep BM=128 (grid >= 316 blocks) via template<MFR>.
//  * hierarchical 3-kernel CSR scan (replaces 1-block serial scan).
//  * fused single-gather segment softmax (deg<=64 register fast path).
// ---------------------------------------------------------------------------

#define LB(x) __launch_bounds__(x)

typedef unsigned short u16;
typedef unsigned int u32;
typedef __attribute__((ext_vector_type(8))) short bf16x8;
typedef __attribute__((ext_vector_type(4))) float f32x4;

__device__ __forceinline__ float b2f(u16 u) {
    union { float f; u32 u; } x;
    x.u = ((u32)u) << 16;
    return x.f;
}
__device__ __forceinline__ u16 f2b(float f) {
    u32 u = __float_as_uint(f);
    u = (u + 0x7FFFu + ((u >> 16) & 1u)) >> 16;   // RNE
    return (u16)u;
}
__device__ __forceinline__ void lds_cp16(const void* g, void* l) {
    __builtin_amdgcn_global_load_lds(
        (const __attribute__((address_space(1))) unsigned int*)g,
        (__attribute__((address_space(3))) unsigned int*)l, 16, 0, 0);
}

// ---------------- CSR build ----------------
__global__ void k_deg(const int* __restrict__ ei, int E, int Np, int* __restrict__ deg) {
    int e = blockIdx.x * blockDim.x + threadIdx.x;
    if (e >= E + Np) return;
    int dst = (e < E) ? ei[E + e] : (e - E);
    atomicAdd(&deg[dst], 1);
}

// hierarchical scan: s1 = per-block inclusive scan, s2 = scan of block sums,
// s3 = add offsets + build cursor.
__global__ LB(256) void k_s1(const int* __restrict__ deg, int* __restrict__ row_ptr,
                             int* __restrict__ bsum, int n) {
    __shared__ int sh[256];
    int b = blockIdx.x, t = threadIdx.x;
    int i = b * 256 + t;
    int v = (i < n) ? deg[i] : 0;
    sh[t] = v;
    __syncthreads();
    #pragma unroll
    for (int off = 1; off < 256; off <<= 1) {
        int add = (t >= off) ? sh[t - off] : 0;
        __syncthreads();
        sh[t] += add;
        __syncthreads();
    }
    if (i < n) row_ptr[i + 1] = sh[t];
    if (t == 255) bsum[b] = sh[255];
}

__global__ LB(64) void k_s2(int* __restrict__ bsum, int* __restrict__ boff, int nb) {
    __shared__ int sh[64];
    int t = threadIdx.x;
    sh[t] = (t < nb) ? bsum[t] : 0;
    __syncthreads();
    #pragma unroll
    for (int off = 1; off < 64; off <<= 1) {
        int add = (t >= off) ? sh[t - off] : 0;
        __syncthreads();
        sh[t] += add;
        __syncthreads();
    }
    if (t < nb) boff[t] = (t == 0) ? 0 : sh[t - 1];
}

__global__ LB(256) void k_s3(const int* __restrict__ deg, int* __restrict__ row_ptr,
                             const int* __restrict__ boff, int* __restrict__ cursor, int n) {
    int b = blockIdx.x, t = threadIdx.x;
    int i = b * 256 + t;
    if (i == 0) row_ptr[0] = 0;
    if (i < n) {
        int inc = row_ptr[i + 1] + boff[b];
        row_ptr[i + 1] = inc;
        cursor[i] = inc - deg[i];
    }
}

__global__ void k_fill(const int* __restrict__ ei, int E, int Np,
                       int* __restrict__ cursor, int* __restrict__ col_src) {
    int e = blockIdx.x * blockDim.x + threadIdx.x;
    if (e >= E + Np) return;
    int src, dst;
    if (e < E) { src = ei[e]; dst = ei[E + e]; }
    else       { src = dst = e - E; }
    int pos = atomicAdd(&cursor[dst], 1);
    col_src[pos] = src;
}

// ---------------- fp32 -> hi/lo planes ----------------
__global__ void k_pack(const float* __restrict__ in, u16* __restrict__ hi,
                       u16* __restrict__ lo, int n4) {
    int i = blockIdx.x * blockDim.x + threadIdx.x;
    if (i >= n4) return;
    float4 v = ((const float4*)in)[i];
    ushort4 h, l;
    h.x = f2b(v.x); l.x = f2b(v.x - b2f(h.x));
    h.y = f2b(v.y); l.y = f2b(v.y - b2f(h.y));
    h.z = f2b(v.z); l.z = f2b(v.z - b2f(h.z));
    h.w = f2b(v.w); l.w = f2b(v.w - b2f(h.w));
    ((ushort4*)hi)[i] = h;
    ((ushort4*)lo)[i] = l;
}

// ---------------- weight transpose + split: Wt[n][k] planes ----------------
__global__ LB(256) void k_wt_pack(const float* __restrict__ W, u16* __restrict__ Whi,
                                  u16* __restrict__ Wlo, int K, int Nn) {
    __shared__ float sh[32][33];
    int n0 = blockIdx.x * 32, k0 = blockIdx.y * 32;
    int c = threadIdx.x & 31, r0 = threadIdx.x >> 5;
    #pragma unroll
    for (int r = r0; r < 32; r += 8)
        sh[r][c] = W[(size_t)(k0 + r) * Nn + n0 + c];
    __syncthreads();
    #pragma unroll
    for (int r = r0; r < 32; r += 8) {
        float v = sh[c][r];
        u16 hi = f2b(v);
        Whi[(size_t)(n0 + r) * K + k0 + c] = hi;
        Wlo[(size_t)(n0 + r) * K + k0 + c] = f2b(v - b2f(hi));
    }
}

// ---------------- split-plane MFMA GEMM: C = A[M,K] @ Bt[Nn,K]^T -----------
// template MFR = m-fragments per wave (8 -> BM=256 wave 128x64; 4 -> BM=128
// wave 64x64). BN=128, BK=32, 4 waves. LDS XOR swizzle (row&7)<<4 with
// inverse-permuted global_load_lds source (both-sides-or-neither rule).
template<int MFR>
__global__ LB(256) void k_gemm_pl(const u16* __restrict__ Ahi, const u16* __restrict__ Alo,
                                  const u16* __restrict__ Bhi, const u16* __restrict__ Blo,
                                  const float* __restrict__ bias,
                                  u16* __restrict__ Chi, u16* __restrict__ Clo,
                                  int M, int K, int Nn) {
    constexpr int BM = MFR * 32;
    __shared__ u16 AsHi[BM * 32], AsLo[BM * 32];
    __shared__ u16 BsHi[128 * 32], BsLo[128 * 32];
    const int tid  = threadIdx.x;
    const int lane = tid & 63;
    const int w    = tid >> 6;
    const int wr   = w >> 1;
    const int wc   = w & 1;
    const int row0 = blockIdx.y * BM;
    const int col0 = blockIdx.x * 128;
    const int ln15 = lane & 15;
    const int lq   = lane >> 4;

    f32x4 acc[MFR][4];
    #pragma unroll
    for (int m = 0; m < MFR; ++m)
        #pragma unroll
        for (int n = 0; n < 4; ++n) acc[m][n] = (f32x4){0.f, 0.f, 0.f, 0.f};

    for (int k0 = 0; k0 < K; k0 += 32) {
        // A planes: BM*4 16B-chunks each; MFR/2 per thread per plane.
        #pragma unroll
        for (int i = 0; i < MFR / 2; ++i) {
            int c = i * 256 + tid;
            int r  = 2 * (c >> 3) + (((c >> 2) ^ (c >> 4)) & 1);
            int kc = (c & 3) ^ (r & 3);
            int gra = row0 + r; if (gra >= M) gra = M - 1;   // tail clamp
            size_t ga = (size_t)gra * K + k0 + kc * 8;
            lds_cp16(Ahi + ga, (char*)AsHi + c * 16);
            lds_cp16(Alo + ga, (char*)AsLo + c * 16);
        }
        // B planes: 512 chunks each; 2 per thread per plane.
        #pragma unroll
        for (int i = 0; i < 2; ++i) {
            int c = i * 256 + tid;
            int r  = 2 * (c >> 3) + (((c >> 2) ^ (c >> 4)) & 1);
            int kc = (c & 3) ^ (r & 3);
            size_t gb = (size_t)(col0 + r) * K + k0 + kc * 8;
            lds_cp16(Bhi + gb, (char*)BsHi + c * 16);
            lds_cp16(Blo + gb, (char*)BsLo + c * 16);
        }
        __syncthreads();
        bf16x8 bh[4], bl[4];
        #pragma unroll
        for (int n = 0; n < 4; ++n) {
            int row = wc * 64 + n * 16 + ln15;
            int byo = (row * 64 + lq * 16) ^ ((row & 7) << 4);
            bh[n] = *(const bf16x8*)((const char*)BsHi + byo);
            bl[n] = *(const bf16x8*)((const char*)BsLo + byo);
        }
        #pragma unroll
        for (int m = 0; m < MFR; ++m) {
            int row = wr * (MFR * 16) + m * 16 + ln15;
            int byo = (row * 64 + lq * 16) ^ ((row & 7) << 4);
            bf16x8 ah = *(const bf16x8*)((const char*)AsHi + byo);
            bf16x8 al = *(const bf16x8*)((const char*)AsLo + byo);
            #pragma unroll
            for (int n = 0; n < 4; ++n) {
                acc[m][n] = __builtin_amdgcn_mfma_f32_16x16x32_bf16(al, bh[n], acc[m][n], 0, 0, 0);
                acc[m][n] = __builtin_amdgcn_mfma_f32_16x16x32_bf16(ah, bl[n], acc[m][n], 0, 0, 0);
                acc[m][n] = __builtin_amdgcn_mfma_f32_16x16x32_bf16(ah, bh[n], acc[m][n], 0, 0, 0);
            }
        }
        __syncthreads();
    }

    // D: col = lane&15, row = (lane>>4)*4 + j  [m89/m91-verified]
    #pragma unroll
    for (int m = 0; m < MFR; ++m) {
        #pragma unroll
        for (int n = 0; n < 4; ++n) {
            int gc = col0 + wc * 64 + n * 16 + ln15;
            float badd = bias ? bias[gc] : 0.f;
            #pragma unroll
            for (int j = 0; j < 4; ++j) {
                int gr = row0 + wr * (MFR * 16) + m * 16 + lq * 4 + j;
                if (gr < M) {
                    float v = acc[m][n][j] + badd;
                    u16 hi = f2b(v);
                    size_t o = (size_t)gr * Nn + gc;
                    Chi[o] = hi;
                    Clo[o] = f2b(v - b2f(hi));
                }
            }
        }
    }
}

// ---------------- attention scalars from hi/lo planes ----------------
// grid = N, block = 64*H; C == 512.
__global__ void k_att(const u16* __restrict__ Hhi, const u16* __restrict__ Hlo,
                      const float* __restrict__ att_s, const float* __restrict__ att_d,
                      float* __restrict__ a_src, float* __restrict__ a_dst,
                      int H, int C) {
    int n = blockIdx.x;
    int w = threadIdx.x >> 6;
    int lane = threadIdx.x & 63;
    size_t o = (size_t)n * H * C + (size_t)w * C + lane * 8;
    bf16x8 vh = *(const bf16x8*)(Hhi + o);
    bf16x8 vl = *(const bf16x8*)(Hlo + o);
    float s1 = 0.f, s2 = 0.f;
    int ob = w * C + lane * 8;
    #pragma unroll
    for (int j = 0; j < 8; ++j) {
        float hv = b2f((u16)vh[j]) + b2f((u16)vl[j]);
        s1 = fmaf(hv, att_s[ob + j], s1);
        s2 = fmaf(hv, att_d[ob + j], s2);
    }
    #pragma unroll
    for (int off = 32; off; off >>= 1) {
        s1 += __shfl_xor(s1, off);
        s2 += __shfl_xor(s2, off);
    }
    if (lane == 0) { a_src[n * H + w] = s1; a_dst[n * H + w] = s2; }
}

// ---------------- fused segment softmax per dst (one wave) ----------------
// fast path deg<=64: single gather into registers, 3 reduces, 1 write.
template<int HH>
__global__ LB(64) void k_softmax(const int* __restrict__ row_ptr, const int* __restrict__ col_src,
                                 const float* __restrict__ a_src, const float* __restrict__ a_dst,
                                 float* __restrict__ alpha) {
    int d = blockIdx.x;
    int t = threadIdx.x;
    int s = row_ptr[d], eend = row_ptr[d + 1];
    int cnt = eend - s;
    float adh[HH];
    #pragma unroll
    for (int h = 0; h < HH; ++h) adh[h] = a_dst[d * HH + h];

    if (cnt <= 64) {
        bool act = t < cnt;
        float av[HH];
        #pragma unroll
        for (int h = 0; h < HH; ++h) av[h] = 0.f;
        if (act) {
            int src = col_src[s + t];
            if (HH == 4) {
                float4 q = ((const float4*)a_src)[src];
                av[0] = q.x; av[1] = q.y; av[2] = q.z; av[3] = q.w;
            } else {
                av[0] = a_src[src];
            }
        }
        float v[HH], m[HH], sum[HH];
        #pragma unroll
        for (int h = 0; h < HH; ++h) {
            float x = av[h] + adh[h];
            x = (x > 0.f) ? x : 0.2f * x;
            v[h] = act ? x : -1e30f;
            m[h] = v[h];
        }
        #pragma unroll
        for (int off = 32; off; off >>= 1)
            #pragma unroll
            for (int h = 0; h < HH; ++h) m[h] = fmaxf(m[h], __shfl_xor(m[h], off));
        #pragma unroll
        for (int h = 0; h < HH; ++h) {
            float e = act ? __expf(v[h] - m[h]) : 0.f;
            v[h] = e;
            sum[h] = e;
        }
        #pragma unroll
        for (int off = 32; off; off >>= 1)
            #pragma unroll
            for (int h = 0; h < HH; ++h) sum[h] += __shfl_xor(sum[h], off);
        if (act) {
            if (HH == 4) {
                float4 o;
                o.x = v[0] / sum[0]; o.y = v[1] / sum[1];
                o.z = v[2] / sum[2]; o.w = v[3] / sum[3];
                ((float4*)alpha)[s + t] = o;
            } else {
                alpha[s + t] = v[0] / sum[0];
            }
        }
        return;
    }

    // generic fallback (deg > 64): 3-pass recompute
    for (int h = 0; h < HH; ++h) {
        float m = -1e30f;
        for (int e = s + t; e < eend; e += 64) {
            float x = a_src[col_src[e] * HH + h] + adh[h];
            x = (x > 0.f) ? x : 0.2f * x;
            m = fmaxf(m, x);
        }
        #pragma unroll
        for (int off = 32; off; off >>= 1) m = fmaxf(m, __shfl_xor(m, off));
        float sum = 0.f;
        for (int e = s + t; e < eend; e += 64) {
            float x = a_src[col_src[e] * HH + h] + adh[h];
            x = (x > 0.f) ? x : 0.2f * x;
            sum += __expf(x - m);
        }
        #pragma unroll
        for (int off = 32; off; off >>= 1) sum += __shfl_xor(sum, off);
        float inv = 1.0f / sum;
        for (int e = s + t; e < eend; e += 64) {
            float x = a_src[col_src[e] * HH + h] + adh[h];
            x = (x > 0.f) ? x : 0.2f * x;
            alpha[e * HH + h] = __expf(x - m) * inv;
        }
    }
}

// ---------------- aggregate: out[d] = sum_e alpha[e,h]*h[src] (+bias,ELU) --
// block = F/8 threads; each thread owns 8 contiguous elements.
template <bool PLANES_OUT, bool ELU_>
__global__ LB(256) void k_agg(const int* __restrict__ row_ptr, const int* __restrict__ col_src,
                              const float* __restrict__ alpha,
                              const u16* __restrict__ Hhi, const u16* __restrict__ Hlo,
                              const float* __restrict__ bias,
                              u16* __restrict__ Ohi, u16* __restrict__ Olo,
                              float* __restrict__ Of, int H, int C) {
    int d = blockIdx.x;
    int tid = threadIdx.x;
    int F = H * C;
    int o = tid * 8;
    int h0 = o / C;   // wave-uniform for C=512
    float acc[8];
    #pragma unroll
    for (int j = 0; j < 8; ++j) acc[j] = 0.f;
    int s = row_ptr[d], eend = row_ptr[d + 1];
    for (int e = s; e < eend; ++e) {
        int src = col_src[e];
        float a = alpha[e * H + h0];
        size_t go = (size_t)src * F + o;
        bf16x8 vh = *(const bf16x8*)(Hhi + go);
        bf16x8 vl = *(const bf16x8*)(Hlo + go);
        #pragma unroll
        for (int j = 0; j < 8; ++j)
            acc[j] = fmaf(a, b2f((u16)vh[j]) + b2f((u16)vl[j]), acc[j]);
    }
    #pragma unroll
    for (int j = 0; j < 8; ++j) {
        acc[j] += bias[o + j];
        if (ELU_) acc[j] = (acc[j] > 0.f) ? acc[j] : __expf(acc[j]) - 1.f;
    }
    if (PLANES_OUT) {
        bf16x8 rh, rl;
        #pragma unroll
        for (int j = 0; j < 8; ++j) {
            u16 hi = f2b(acc[j]);
            rh[j] = (short)hi;
            rl[j] = (short)f2b(acc[j] - b2f(hi));
        }
        *(bf16x8*)(Ohi + (size_t)d * F + o) = rh;
        *(bf16x8*)(Olo + (size_t)d * F + o) = rl;
    } else {
        float* po = Of + (size_t)d * F + o;
        #pragma unroll
        for (int j4 = 0; j4 < 2; ++j4) {
            float4 r;
            r.x = acc[j4 * 4 + 0]; r.y = acc[j4 * 4 + 1];
            r.z = acc[j4 * 4 + 2]; r.w = acc[j4 * 4 + 3];
            *(float4*)&po[j4 * 4] = r;
        }
    }
}

// ---------------------------------------------------------------------------
extern "C" void kernel_launch(void* const* d_in, const int* in_sizes, int n_in,
                              void* d_out, int out_size, void* d_ws, size_t ws_size,
                              hipStream_t stream) {
    const float* x      = (const float*)d_in[0];
    const int*   ei     = (const int*)d_in[1];
    const float* proj_W = (const float*)d_in[2];
    const float* proj_b = (const float*)d_in[3];
    const float* W1  = (const float*)d_in[4];
    const float* as1 = (const float*)d_in[5];
    const float* ad1 = (const float*)d_in[6];
    const float* b1  = (const float*)d_in[7];
    const float* W2  = (const float*)d_in[8];
    const float* as2 = (const float*)d_in[9];
    const float* ad2 = (const float*)d_in[10];
    const float* b2  = (const float*)d_in[11];
    const float* W3  = (const float*)d_in[12];
    const float* as3 = (const float*)d_in[13];
    const float* ad3 = (const float*)d_in[14];
    const float* b3  = (const float*)d_in[15];

    const int N  = in_sizes[0] / 256;   // 10000
    const int E  = in_sizes[1] / 2;     // 160000
    const int Ep = E + N;
    const int NB = (N + 255) / 256;     // 40 scan blocks

    size_t off = 0;
    auto alloc = [&](size_t bytes) -> void* {
        void* p = (char*)d_ws + off;
        off += (bytes + 255) & ~(size_t)255;
        return p;
    };
    u16* bufA_hi = (u16*)alloc((size_t)N * 2048 * 2);
    u16* bufA_lo = (u16*)alloc((size_t)N * 2048 * 2);
    u16* bufB_hi = (u16*)alloc((size_t)N * 2048 * 2);
    u16* bufB_lo = (u16*)alloc((size_t)N * 2048 * 2);
    float* a_src   = (float*)alloc((size_t)N * 4 * 4);
    float* a_dst   = (float*)alloc((size_t)N * 4 * 4);
    float* alpha   = (float*)alloc((size_t)Ep * 4 * 4);
    int*   deg     = (int*)alloc((size_t)N * 4);
    int*   cursor  = (int*)alloc((size_t)N * 4);
    int*   row_ptr = (int*)alloc((size_t)(N + 1) * 4);
    int*   col_src = (int*)alloc((size_t)Ep * 4);
    int*   bsum    = (int*)alloc((size_t)NB * 4);
    int*   boff    = (int*)alloc((size_t)NB * 4);
    (void)ws_size;

    // JIT weight planes live in d_out (16.78 MB <= 20.48 MB); consumed by
    // GEMMs, then fully overwritten by the final aggregate.
    u16* whi = (u16*)d_out;
    u16* wlo = (u16*)d_out + (size_t)2048 * 2048;

    // ---- CSR build ----
    hipMemsetAsync(deg, 0, (size_t)N * 4, stream);
    int eb = (Ep + 255) / 256;
    k_deg<<<eb, 256, 0, stream>>>(ei, E, N, deg);
    k_s1<<<NB, 256, 0, stream>>>(deg, row_ptr, bsum, N);
    k_s2<<<1, 64, 0, stream>>>(bsum, boff, NB);
    k_s3<<<NB, 256, 0, stream>>>(deg, row_ptr, boff, cursor, N);
    k_fill<<<eb, 256, 0, stream>>>(ei, E, N, cursor, col_src);

    const int MB1 = (N + 127) / 128;  // 79  (BM=128 grids)
    const int MB2 = (N + 255) / 256;  // 40  (BM=256 grids)

    // ---- pack x into bufB planes [N,256] ----
    k_pack<<<(N * 256 / 4 + 255) / 256, 256, 0, stream>>>(x, bufB_hi, bufB_lo, N * 256 / 4);

    // ---- proj: bufA = x @ proj_W + proj_b  [N,512]  (BM=128) ----
    k_wt_pack<<<dim3(512 / 32, 256 / 32), 256, 0, stream>>>(proj_W, whi, wlo, 256, 512);
    k_gemm_pl<4><<<dim3(512 / 128, MB1), 256, 0, stream>>>(bufB_hi, bufB_lo, whi, wlo, proj_b,
                                                           bufA_hi, bufA_lo, N, 256, 512);

    // ---- layer 1 (H=4, C=512, concat, ELU)  (BM=256) ----
    k_wt_pack<<<dim3(2048 / 32, 512 / 32), 256, 0, stream>>>(W1, whi, wlo, 512, 2048);
    k_gemm_pl<8><<<dim3(2048 / 128, MB2), 256, 0, stream>>>(bufA_hi, bufA_lo, whi, wlo, nullptr,
                                                            bufB_hi, bufB_lo, N, 512, 2048);
    k_att<<<N, 256, 0, stream>>>(bufB_hi, bufB_lo, as1, ad1, a_src, a_dst, 4, 512);
    k_softmax<4><<<N, 64, 0, stream>>>(row_ptr, col_src, a_src, a_dst, alpha);
    k_agg<true, true><<<N, 256, 0, stream>>>(row_ptr, col_src, alpha, bufB_hi, bufB_lo,
                                             b1, bufA_hi, bufA_lo, nullptr, 4, 512);

    // ---- layer 2 (H=4, C=512, concat, ELU)  (BM=256) ----
    k_wt_pack<<<dim3(2048 / 32, 2048 / 32), 256, 0, stream>>>(W2, whi, wlo, 2048, 2048);
    k_gemm_pl<8><<<dim3(2048 / 128, MB2), 256, 0, stream>>>(bufA_hi, bufA_lo, whi, wlo, nullptr,
                                                            bufB_hi, bufB_lo, N, 2048, 2048);
    k_att<<<N, 256, 0, stream>>>(bufB_hi, bufB_lo, as2, ad2, a_src, a_dst, 4, 512);
    k_softmax<4><<<N, 64, 0, stream>>>(row_ptr, col_src, a_src, a_dst, alpha);
    k_agg<true, true><<<N, 256, 0, stream>>>(row_ptr, col_src, alpha, bufB_hi, bufB_lo,
                                             b2, bufA_hi, bufA_lo, nullptr, 4, 512);

    // ---- layer 3 (H=1, C=512, mean over single head = identity, no ELU) ----
    k_wt_pack<<<dim3(512 / 32, 2048 / 32), 256, 0, stream>>>(W3, whi, wlo, 2048, 512);
    k_gemm_pl<4><<<dim3(512 / 128, MB1), 256, 0, stream>>>(bufA_hi, bufA_lo, whi, wlo, nullptr,
                                                           bufB_hi, bufB_lo, N, 2048, 512);
    k_att<<<N, 64, 0, stream>>>(bufB_hi, bufB_lo, as3, ad3, a_src, a_dst, 1, 512);
    k_softmax<1><<<N, 64, 0, stream>>>(row_ptr, col_src, a_src, a_dst, alpha);
    k_agg<false, false><<<N, 64, 0, stream>>>(row_ptr, col_src, alpha, bufB_hi, bufB_lo,
                                              b3, nullptr, nullptr, (float*)d_out, 1, 512);
}

// Round 6
// 1066.472 us; speedup vs baseline: 1.2060x; 1.2060x over previous
//
#include <hip/hip_runtime.h>
#include <hip/hip_bf16.h>

// ---------------------------------------------------------------------------
// GAT encoder, round 6: emulated-fp32 GEMM via hi/lo split bf16 MFMA
// (3 products: Ahi*Bhi + Ahi*Blo + Alo*Bhi, fp32 accum -> ~2^-17 relative).
// Round-6 changes vs round-5:
//  * GEMM geometry reverted to round-4 proven config (BM=128, 4 waves,
//    32KB LDS, occupancy 19%) -- BM=256 regressed via occupancy loss.
//  * Big GEMMs store C as packed u32 {hi,lo} -> full 64B-line stores
//    (plane stores were 2B/lane partial-line RMW). att/agg read packed;
//    agg emits planes (coalesced) so GEMM A-inputs stay plane-format.
//  * keeps hierarchical scan + fused single-gather softmax.
// ---------------------------------------------------------------------------

#define LB(x) __launch_bounds__(x)

typedef unsigned short u16;
typedef unsigned int u32;
typedef __attribute__((ext_vector_type(8))) short bf16x8;
typedef __attribute__((ext_vector_type(4))) float f32x4;

__device__ __forceinline__ float b2f(u16 u) {
    union { float f; u32 u; } x;
    x.u = ((u32)u) << 16;
    return x.f;
}
__device__ __forceinline__ u16 f2b(float f) {
    u32 u = __float_as_uint(f);
    u = (u + 0x7FFFu + ((u >> 16) & 1u)) >> 16;   // RNE
    return (u16)u;
}
__device__ __forceinline__ float rec2(u32 p) {
    return b2f((u16)(p >> 16)) + b2f((u16)p);
}
__device__ __forceinline__ void lds_cp16(const void* g, void* l) {
    __builtin_amdgcn_global_load_lds(
        (const __attribute__((address_space(1))) unsigned int*)g,
        (__attribute__((address_space(3))) unsigned int*)l, 16, 0, 0);
}

// ---------------- CSR build ----------------
__global__ void k_deg(const int* __restrict__ ei, int E, int Np, int* __restrict__ deg) {
    int e = blockIdx.x * blockDim.x + threadIdx.x;
    if (e >= E + Np) return;
    int dst = (e < E) ? ei[E + e] : (e - E);
    atomicAdd(&deg[dst], 1);
}

__global__ LB(256) void k_s1(const int* __restrict__ deg, int* __restrict__ row_ptr,
                             int* __restrict__ bsum, int n) {
    __shared__ int sh[256];
    int b = blockIdx.x, t = threadIdx.x;
    int i = b * 256 + t;
    int v = (i < n) ? deg[i] : 0;
    sh[t] = v;
    __syncthreads();
    #pragma unroll
    for (int off = 1; off < 256; off <<= 1) {
        int add = (t >= off) ? sh[t - off] : 0;
        __syncthreads();
        sh[t] += add;
        __syncthreads();
    }
    if (i < n) row_ptr[i + 1] = sh[t];
    if (t == 255) bsum[b] = sh[255];
}

__global__ LB(64) void k_s2(int* __restrict__ bsum, int* __restrict__ boff, int nb) {
    __shared__ int sh[64];
    int t = threadIdx.x;
    sh[t] = (t < nb) ? bsum[t] : 0;
    __syncthreads();
    #pragma unroll
    for (int off = 1; off < 64; off <<= 1) {
        int add = (t >= off) ? sh[t - off] : 0;
        __syncthreads();
        sh[t] += add;
        __syncthreads();
    }
    if (t < nb) boff[t] = (t == 0) ? 0 : sh[t - 1];
}

__global__ LB(256) void k_s3(const int* __restrict__ deg, int* __restrict__ row_ptr,
                             const int* __restrict__ boff, int* __restrict__ cursor, int n) {
    int b = blockIdx.x, t = threadIdx.x;
    int i = b * 256 + t;
    if (i == 0) row_ptr[0] = 0;
    if (i < n) {
        int inc = row_ptr[i + 1] + boff[b];
        row_ptr[i + 1] = inc;
        cursor[i] = inc - deg[i];
    }
}

__global__ void k_fill(const int* __restrict__ ei, int E, int Np,
                       int* __restrict__ cursor, int* __restrict__ col_src) {
    int e = blockIdx.x * blockDim.x + threadIdx.x;
    if (e >= E + Np) return;
    int src, dst;
    if (e < E) { src = ei[e]; dst = ei[E + e]; }
    else       { src = dst = e - E; }
    int pos = atomicAdd(&cursor[dst], 1);
    col_src[pos] = src;
}

// ---------------- fp32 -> hi/lo planes ----------------
__global__ void k_pack(const float* __restrict__ in, u16* __restrict__ hi,
                       u16* __restrict__ lo, int n4) {
    int i = blockIdx.x * blockDim.x + threadIdx.x;
    if (i >= n4) return;
    float4 v = ((const float4*)in)[i];
    ushort4 h, l;
    h.x = f2b(v.x); l.x = f2b(v.x - b2f(h.x));
    h.y = f2b(v.y); l.y = f2b(v.y - b2f(h.y));
    h.z = f2b(v.z); l.z = f2b(v.z - b2f(h.z));
    h.w = f2b(v.w); l.w = f2b(v.w - b2f(h.w));
    ((ushort4*)hi)[i] = h;
    ((ushort4*)lo)[i] = l;
}

// ---------------- weight transpose + split: Wt[n][k] planes ----------------
__global__ LB(256) void k_wt_pack(const float* __restrict__ W, u16* __restrict__ Whi,
                                  u16* __restrict__ Wlo, int K, int Nn) {
    __shared__ float sh[32][33];
    int n0 = blockIdx.x * 32, k0 = blockIdx.y * 32;
    int c = threadIdx.x & 31, r0 = threadIdx.x >> 5;
    #pragma unroll
    for (int r = r0; r < 32; r += 8)
        sh[r][c] = W[(size_t)(k0 + r) * Nn + n0 + c];
    __syncthreads();
    #pragma unroll
    for (int r = r0; r < 32; r += 8) {
        float v = sh[c][r];
        u16 hi = f2b(v);
        Whi[(size_t)(n0 + r) * K + k0 + c] = hi;
        Wlo[(size_t)(n0 + r) * K + k0 + c] = f2b(v - b2f(hi));
    }
}

// ---------------- split-plane MFMA GEMM: C = A[M,K] @ Bt[Nn,K]^T -----------
// Round-4 geometry: 128x128 tile, BK=32, 4 waves (2x2), 64x64/wave,
// 48 MFMA/K-step/wave. LDS XOR swizzle (row&7)<<4, inverse-permuted
// global_load_lds source. C output: packed u32 (PACKC) or hi/lo planes.
template<bool PACKC>
__global__ LB(256) void k_gemm_pl(const u16* __restrict__ Ahi, const u16* __restrict__ Alo,
                                  const u16* __restrict__ Bhi, const u16* __restrict__ Blo,
                                  const float* __restrict__ bias,
                                  u16* __restrict__ Chi, u16* __restrict__ Clo,
                                  u32* __restrict__ Cpk,
                                  int M, int K, int Nn) {
    __shared__ u16 AsHi[128 * 32], AsLo[128 * 32], BsHi[128 * 32], BsLo[128 * 32];
    const int tid  = threadIdx.x;
    const int lane = tid & 63;
    const int w    = tid >> 6;
    const int wr   = w >> 1;
    const int wc   = w & 1;
    const int row0 = blockIdx.y * 128;
    const int col0 = blockIdx.x * 128;
    const int ln15 = lane & 15;
    const int lq   = lane >> 4;

    f32x4 acc[4][4];
    #pragma unroll
    for (int m = 0; m < 4; ++m)
        #pragma unroll
        for (int n = 0; n < 4; ++n) acc[m][n] = (f32x4){0.f, 0.f, 0.f, 0.f};

    for (int k0 = 0; k0 < K; k0 += 32) {
        // stage: 512 16B-chunks per plane-tile, 2 per thread per plane.
        #pragma unroll
        for (int i = 0; i < 2; ++i) {
            int c = i * 256 + tid;
            // inverse of swizzle: slot c holds element (r, kc)
            int r  = 2 * (c >> 3) + (((c >> 2) ^ (c >> 4)) & 1);
            int kc = (c & 3) ^ (r & 3);
            int gra = row0 + r; if (gra >= M) gra = M - 1;   // tail clamp
            size_t ga = (size_t)gra * K + k0 + kc * 8;
            size_t gb = (size_t)(col0 + r) * K + k0 + kc * 8;
            lds_cp16(Ahi + ga, (char*)AsHi + c * 16);
            lds_cp16(Alo + ga, (char*)AsLo + c * 16);
            lds_cp16(Bhi + gb, (char*)BsHi + c * 16);
            lds_cp16(Blo + gb, (char*)BsLo + c * 16);
        }
        __syncthreads();
        bf16x8 ah[4], al[4], bh[4], bl[4];
        #pragma unroll
        for (int m = 0; m < 4; ++m) {
            int row = wr * 64 + m * 16 + ln15;
            int byo = (row * 64 + lq * 16) ^ ((row & 7) << 4);
            ah[m] = *(const bf16x8*)((const char*)AsHi + byo);
            al[m] = *(const bf16x8*)((const char*)AsLo + byo);
        }
        #pragma unroll
        for (int n = 0; n < 4; ++n) {
            int row = wc * 64 + n * 16 + ln15;
            int byo = (row * 64 + lq * 16) ^ ((row & 7) << 4);
            bh[n] = *(const bf16x8*)((const char*)BsHi + byo);
            bl[n] = *(const bf16x8*)((const char*)BsLo + byo);
        }
        #pragma unroll
        for (int m = 0; m < 4; ++m)
            #pragma unroll
            for (int n = 0; n < 4; ++n) {
                acc[m][n] = __builtin_amdgcn_mfma_f32_16x16x32_bf16(al[m], bh[n], acc[m][n], 0, 0, 0);
                acc[m][n] = __builtin_amdgcn_mfma_f32_16x16x32_bf16(ah[m], bl[n], acc[m][n], 0, 0, 0);
                acc[m][n] = __builtin_amdgcn_mfma_f32_16x16x32_bf16(ah[m], bh[n], acc[m][n], 0, 0, 0);
            }
        __syncthreads();
    }

    // D: col = lane&15, row = (lane>>4)*4 + j  [m89/m91-verified]
    #pragma unroll
    for (int m = 0; m < 4; ++m) {
        #pragma unroll
        for (int n = 0; n < 4; ++n) {
            int gc = col0 + wc * 64 + n * 16 + ln15;
            float badd = bias ? bias[gc] : 0.f;
            #pragma unroll
            for (int j = 0; j < 4; ++j) {
                int gr = row0 + wr * 64 + m * 16 + lq * 4 + j;
                if (gr < M) {
                    float v = acc[m][n][j] + badd;
                    u16 hi = f2b(v);
                    u16 lo = f2b(v - b2f(hi));
                    size_t o = (size_t)gr * Nn + gc;
                    if (PACKC) {
                        Cpk[o] = ((u32)hi << 16) | (u32)lo;   // 64B full-line stores
                    } else {
                        Chi[o] = hi;
                        Clo[o] = lo;
                    }
                }
            }
        }
    }
}

// ---------------- attention scalars from packed h ----------------
// grid = N, block = 64*H; C == 512.
__global__ void k_att(const u32* __restrict__ h_pk,
                      const float* __restrict__ att_s, const float* __restrict__ att_d,
                      float* __restrict__ a_src, float* __restrict__ a_dst,
                      int H, int C) {
    int n = blockIdx.x;
    int w = threadIdx.x >> 6;
    int lane = threadIdx.x & 63;
    const u32* hp = h_pk + (size_t)n * H * C + (size_t)w * C + lane * 8;
    uint4 p0 = ((const uint4*)hp)[0];
    uint4 p1 = ((const uint4*)hp)[1];
    float hv[8] = { rec2(p0.x), rec2(p0.y), rec2(p0.z), rec2(p0.w),
                    rec2(p1.x), rec2(p1.y), rec2(p1.z), rec2(p1.w) };
    float s1 = 0.f, s2 = 0.f;
    int ob = w * C + lane * 8;
    #pragma unroll
    for (int j = 0; j < 8; ++j) {
        s1 = fmaf(hv[j], att_s[ob + j], s1);
        s2 = fmaf(hv[j], att_d[ob + j], s2);
    }
    #pragma unroll
    for (int off = 32; off; off >>= 1) {
        s1 += __shfl_xor(s1, off);
        s2 += __shfl_xor(s2, off);
    }
    if (lane == 0) { a_src[n * H + w] = s1; a_dst[n * H + w] = s2; }
}

// ---------------- fused segment softmax per dst (one wave) ----------------
template<int HH>
__global__ LB(64) void k_softmax(const int* __restrict__ row_ptr, const int* __restrict__ col_src,
                                 const float* __restrict__ a_src, const float* __restrict__ a_dst,
                                 float* __restrict__ alpha) {
    int d = blockIdx.x;
    int t = threadIdx.x;
    int s = row_ptr[d], eend = row_ptr[d + 1];
    int cnt = eend - s;
    float adh[HH];
    #pragma unroll
    for (int h = 0; h < HH; ++h) adh[h] = a_dst[d * HH + h];

    if (cnt <= 64) {
        bool act = t < cnt;
        float av[HH];
        #pragma unroll
        for (int h = 0; h < HH; ++h) av[h] = 0.f;
        if (act) {
            int src = col_src[s + t];
            if (HH == 4) {
                float4 q = ((const float4*)a_src)[src];
                av[0] = q.x; av[1] = q.y; av[2] = q.z; av[3] = q.w;
            } else {
                av[0] = a_src[src];
            }
        }
        float v[HH], m[HH], sum[HH];
        #pragma unroll
        for (int h = 0; h < HH; ++h) {
            float x = av[h] + adh[h];
            x = (x > 0.f) ? x : 0.2f * x;
            v[h] = act ? x : -1e30f;
            m[h] = v[h];
        }
        #pragma unroll
        for (int off = 32; off; off >>= 1)
            #pragma unroll
            for (int h = 0; h < HH; ++h) m[h] = fmaxf(m[h], __shfl_xor(m[h], off));
        #pragma unroll
        for (int h = 0; h < HH; ++h) {
            float e = act ? __expf(v[h] - m[h]) : 0.f;
            v[h] = e;
            sum[h] = e;
        }
        #pragma unroll
        for (int off = 32; off; off >>= 1)
            #pragma unroll
            for (int h = 0; h < HH; ++h) sum[h] += __shfl_xor(sum[h], off);
        if (act) {
            if (HH == 4) {
                float4 o;
                o.x = v[0] / sum[0]; o.y = v[1] / sum[1];
                o.z = v[2] / sum[2]; o.w = v[3] / sum[3];
                ((float4*)alpha)[s + t] = o;
            } else {
                alpha[s + t] = v[0] / sum[0];
            }
        }
        return;
    }

    // generic fallback (deg > 64): 3-pass recompute
    for (int h = 0; h < HH; ++h) {
        float m = -1e30f;
        for (int e = s + t; e < eend; e += 64) {
            float x = a_src[col_src[e] * HH + h] + adh[h];
            x = (x > 0.f) ? x : 0.2f * x;
            m = fmaxf(m, x);
        }
        #pragma unroll
        for (int off = 32; off; off >>= 1) m = fmaxf(m, __shfl_xor(m, off));
        float sum = 0.f;
        for (int e = s + t; e < eend; e += 64) {
            float x = a_src[col_src[e] * HH + h] + adh[h];
            x = (x > 0.f) ? x : 0.2f * x;
            sum += __expf(x - m);
        }
        #pragma unroll
        for (int off = 32; off; off >>= 1) sum += __shfl_xor(sum, off);
        float inv = 1.0f / sum;
        for (int e = s + t; e < eend; e += 64) {
            float x = a_src[col_src[e] * HH + h] + adh[h];
            x = (x > 0.f) ? x : 0.2f * x;
            alpha[e * HH + h] = __expf(x - m) * inv;
        }
    }
}

// ---------------- aggregate: out[d] = sum_e alpha[e,h]*h[src] (+bias,ELU) --
// input packed u32; output planes (coalesced rows) or fp32 final.
template <bool PLANES_OUT, bool ELU_>
__global__ LB(256) void k_agg(const int* __restrict__ row_ptr, const int* __restrict__ col_src,
                              const float* __restrict__ alpha,
                              const u32* __restrict__ h_pk,
                              const float* __restrict__ bias,
                              u16* __restrict__ Ohi, u16* __restrict__ Olo,
                              float* __restrict__ Of, int H, int C) {
    int d = blockIdx.x;
    int tid = threadIdx.x;
    int F = H * C;
    int o = tid * 8;
    int h0 = o / C;   // wave-uniform for C=512
    float acc[8];
    #pragma unroll
    for (int j = 0; j < 8; ++j) acc[j] = 0.f;
    int s = row_ptr[d], eend = row_ptr[d + 1];
    for (int e = s; e < eend; ++e) {
        int src = col_src[e];
        float a = alpha[e * H + h0];
        const uint4* hp = (const uint4*)(h_pk + (size_t)src * F + o);
        uint4 p0 = hp[0], p1 = hp[1];
        acc[0] = fmaf(a, rec2(p0.x), acc[0]);
        acc[1] = fmaf(a, rec2(p0.y), acc[1]);
        acc[2] = fmaf(a, rec2(p0.z), acc[2]);
        acc[3] = fmaf(a, rec2(p0.w), acc[3]);
        acc[4] = fmaf(a, rec2(p1.x), acc[4]);
        acc[5] = fmaf(a, rec2(p1.y), acc[5]);
        acc[6] = fmaf(a, rec2(p1.z), acc[6]);
        acc[7] = fmaf(a, rec2(p1.w), acc[7]);
    }
    #pragma unroll
    for (int j = 0; j < 8; ++j) {
        acc[j] += bias[o + j];
        if (ELU_) acc[j] = (acc[j] > 0.f) ? acc[j] : __expf(acc[j]) - 1.f;
    }
    if (PLANES_OUT) {
        bf16x8 rh, rl;
        #pragma unroll
        for (int j = 0; j < 8; ++j) {
            u16 hi = f2b(acc[j]);
            rh[j] = (short)hi;
            rl[j] = (short)f2b(acc[j] - b2f(hi));
        }
        *(bf16x8*)(Ohi + (size_t)d * F + o) = rh;
        *(bf16x8*)(Olo + (size_t)d * F + o) = rl;
    } else {
        float* po = Of + (size_t)d * F + o;
        #pragma unroll
        for (int j4 = 0; j4 < 2; ++j4) {
            float4 r;
            r.x = acc[j4 * 4 + 0]; r.y = acc[j4 * 4 + 1];
            r.z = acc[j4 * 4 + 2]; r.w = acc[j4 * 4 + 3];
            *(float4*)&po[j4 * 4] = r;
        }
    }
}

// ---------------------------------------------------------------------------
extern "C" void kernel_launch(void* const* d_in, const int* in_sizes, int n_in,
                              void* d_out, int out_size, void* d_ws, size_t ws_size,
                              hipStream_t stream) {
    const float* x      = (const float*)d_in[0];
    const int*   ei     = (const int*)d_in[1];
    const float* proj_W = (const float*)d_in[2];
    const float* proj_b = (const float*)d_in[3];
    const float* W1  = (const float*)d_in[4];
    const float* as1 = (const float*)d_in[5];
    const float* ad1 = (const float*)d_in[6];
    const float* b1  = (const float*)d_in[7];
    const float* W2  = (const float*)d_in[8];
    const float* as2 = (const float*)d_in[9];
    const float* ad2 = (const float*)d_in[10];
    const float* b2  = (const float*)d_in[11];
    const float* W3  = (const float*)d_in[12];
    const float* as3 = (const float*)d_in[13];
    const float* ad3 = (const float*)d_in[14];
    const float* b3  = (const float*)d_in[15];

    const int N  = in_sizes[0] / 256;   // 10000
    const int E  = in_sizes[1] / 2;     // 160000
    const int Ep = E + N;
    const int NB = (N + 255) / 256;     // 40 scan blocks

    size_t off = 0;
    auto alloc = [&](size_t bytes) -> void* {
        void* p = (char*)d_ws + off;
        off += (bytes + 255) & ~(size_t)255;
        return p;
    };
    u16* bufA_hi = (u16*)alloc((size_t)N * 2048 * 2);   // GEMM A input planes
    u16* bufA_lo = (u16*)alloc((size_t)N * 2048 * 2);
    u32* bufPk   = (u32*)alloc((size_t)N * 2048 * 4);   // packed GEMM output
    float* a_src   = (float*)alloc((size_t)N * 4 * 4);
    float* a_dst   = (float*)alloc((size_t)N * 4 * 4);
    float* alpha   = (float*)alloc((size_t)Ep * 4 * 4);
    int*   deg     = (int*)alloc((size_t)N * 4);
    int*   cursor  = (int*)alloc((size_t)N * 4);
    int*   row_ptr = (int*)alloc((size_t)(N + 1) * 4);
    int*   col_src = (int*)alloc((size_t)Ep * 4);
    int*   bsum    = (int*)alloc((size_t)NB * 4);
    int*   boff    = (int*)alloc((size_t)NB * 4);
    (void)ws_size;

    // JIT weight planes in d_out (16.78 MB <= 20.48 MB); fully overwritten
    // by the final aggregate afterwards.
    u16* whi = (u16*)d_out;
    u16* wlo = (u16*)d_out + (size_t)2048 * 2048;

    // ---- CSR build ----
    hipMemsetAsync(deg, 0, (size_t)N * 4, stream);
    int eb = (Ep + 255) / 256;
    k_deg<<<eb, 256, 0, stream>>>(ei, E, N, deg);
    k_s1<<<NB, 256, 0, stream>>>(deg, row_ptr, bsum, N);
    k_s2<<<1, 64, 0, stream>>>(bsum, boff, NB);
    k_s3<<<NB, 256, 0, stream>>>(deg, row_ptr, boff, cursor, N);
    k_fill<<<eb, 256, 0, stream>>>(ei, E, N, cursor, col_src);

    const int MB1 = (N + 127) / 128;  // 79

    // ---- pack x into bufA planes [N,256] (proj A input) ----
    k_pack<<<(N * 256 / 4 + 255) / 256, 256, 0, stream>>>(x, bufA_hi, bufA_lo, N * 256 / 4);

    // ---- proj: planes out (feeds L1 GEMM as A). x planes in bufA; write
    //      proj planes into the upper halves? No: proj writes its own planes.
    //      Use bufPk's space reinterpreted as two u16 planes for proj output.
    u16* proj_hi = (u16*)bufPk;                       // [N,512] u16
    u16* proj_lo = (u16*)bufPk + (size_t)N * 512;     // [N,512] u16 (fits in 80MB)
    k_wt_pack<<<dim3(512 / 32, 256 / 32), 256, 0, stream>>>(proj_W, whi, wlo, 256, 512);
    k_gemm_pl<false><<<dim3(512 / 128, MB1), 256, 0, stream>>>(
        bufA_hi, bufA_lo, whi, wlo, proj_b, proj_hi, proj_lo, nullptr, N, 256, 512);

    // ---- layer 1 (H=4, C=512, concat, ELU) ----
    k_wt_pack<<<dim3(2048 / 32, 512 / 32), 256, 0, stream>>>(W1, whi, wlo, 512, 2048);
    // A = proj planes (in bufPk space); C packed -> cannot alias bufPk!
    // Write L1 packed output into bufA region? bufA planes (A input of proj)
    // are dead now, and L1's A is proj planes. bufA = 2x40MB = 80MB: use as
    // packed u32 buffer for L1 output.
    u32* l1pk = (u32*)bufA_hi;   // [N,2048] u32 = 80MB spans bufA_hi+bufA_lo
    k_gemm_pl<true><<<dim3(2048 / 128, MB1), 256, 0, stream>>>(
        proj_hi, proj_lo, whi, wlo, nullptr, nullptr, nullptr, l1pk, N, 512, 2048);
    k_att<<<N, 256, 0, stream>>>(l1pk, as1, ad1, a_src, a_dst, 4, 512);
    k_softmax<4><<<N, 64, 0, stream>>>(row_ptr, col_src, a_src, a_dst, alpha);
    // agg: packed in (l1pk), planes out -> bufPk space (proj planes dead)
    u16* h1_hi = (u16*)bufPk;                         // [N,2048] u16
    u16* h1_lo = (u16*)bufPk + (size_t)N * 2048;      // [N,2048] u16 (80MB total)
    k_agg<true, true><<<N, 256, 0, stream>>>(row_ptr, col_src, alpha, l1pk,
                                             b1, h1_hi, h1_lo, nullptr, 4, 512);

    // ---- layer 2 (H=4, C=512, concat, ELU) ----
    k_wt_pack<<<dim3(2048 / 32, 2048 / 32), 256, 0, stream>>>(W2, whi, wlo, 2048, 2048);
    u32* l2pk = (u32*)bufA_hi;   // reuse 80MB region (l1pk dead after agg)
    k_gemm_pl<true><<<dim3(2048 / 128, MB1), 256, 0, stream>>>(
        h1_hi, h1_lo, whi, wlo, nullptr, nullptr, nullptr, l2pk, N, 2048, 2048);
    k_att<<<N, 256, 0, stream>>>(l2pk, as2, ad2, a_src, a_dst, 4, 512);
    k_softmax<4><<<N, 64, 0, stream>>>(row_ptr, col_src, a_src, a_dst, alpha);
    u16* h2_hi = (u16*)bufPk;
    u16* h2_lo = (u16*)bufPk + (size_t)N * 2048;
    k_agg<true, true><<<N, 256, 0, stream>>>(row_ptr, col_src, alpha, l2pk,
                                             b2, h2_hi, h2_lo, nullptr, 4, 512);

    // ---- layer 3 (H=1, C=512, mean over single head = identity, no ELU) ----
    k_wt_pack<<<dim3(512 / 32, 2048 / 32), 256, 0, stream>>>(W3, whi, wlo, 2048, 512);
    u32* l3pk = (u32*)bufA_hi;   // [N,512] u32 (20MB of the 80MB region)
    k_gemm_pl<true><<<dim3(512 / 128, MB1), 256, 0, stream>>>(
        h2_hi, h2_lo, whi, wlo, nullptr, nullptr, nullptr, l3pk, N, 2048, 512);
    k_att<<<N, 64, 0, stream>>>(l3pk, as3, ad3, a_src, a_dst, 1, 512);
    k_softmax<1><<<N, 64, 0, stream>>>(row_ptr, col_src, a_src, a_dst, alpha);
    k_agg<false, false><<<N, 64, 0, stream>>>(row_ptr, col_src, alpha, l3pk,
                                              b3, nullptr, nullptr, (float*)d_out, 1, 512);
}